// Round 18
// baseline (525.027 us; speedup 1.0000x reference)
//
#include <hip/hip_runtime.h>

// FlowExp: v = flow/2^8; repeat 8x: v <- trilinear_pull(v, identity + v)
// Invariant: ||v||inf <= max|flow|/256 ~ 0.023 < 1 for ALL steps (convex
// combinations, zero-masked) -> one step reaches <= +-1 voxel -> TWO fused
// steps need halo 2 only. floor(x+vx) in {x-1,x}: sign tests, no clamps in
// the gather; out-of-bounds folded into z-weights (m=0).
//
// R18: mids are mixed-r/w-BW bound (~4.2 TB/s effective; overlap/occupancy/
// wide-LDS-read levers all null, conflicts layout-invariant) -> cut traffic
// 2x by fusing 2 steps/kernel. Per block: DMA-stage v_k (halo 2, 36x12x8)
// -> compute v_{k+1} on the halo-1 tile (34x10x6) into REGISTERS (8 vox/thr)
// at CLAMPED absolute positions (bit-identical to unfused halo staging) ->
// barrier -> overwrite LDS with v_{k+1} -> barrier -> gather v_{k+2} core
// tile -> global. Intermediate never touches HBM: 8 steps = 4 kernels.
// Keeps: full-wave padded DMA (R13), hoisted addressing (R12), XCD swizzle.

#define BB 2
#define DD 160
#define HH 192
#define WW 160

constexpr int HW    = HH * WW;            // 30720
constexpr int PLANE = DD * HW;            // 4,915,200
constexpr int TX = 32, TY = 8, TZ = 4;

// staged v_k tile (halo 2)
constexpr int S2X = TX + 4, S2Y = TY + 4, S2Z = TZ + 4;   // 36 x 12 x 8
constexpr int S2YX = S2Y * S2X;           // 432 voxels / slice
constexpr int STG_SLICE = 3 * S2YX;       // 1296 payload floats
constexpr int STG_P = 1536;               // padded: exactly 6 full-wave issues
constexpr int STG_K = STG_P / 256;        // 6

// intermediate v_{k+1} tile (halo 1)
constexpr int S1X = TX + 2, S1Y = TY + 2, S1Z = TZ + 2;   // 34 x 10 x 6
constexpr int S1YX = S1Y * S1X;           // 340
constexpr int INT_P = 1024;               // padded slice stride
constexpr int NI = S1Z * S1YX;            // 2040 intermediate voxels
constexpr int NIT = (NI + 255) / 256;     // 8 per thread

constexpr int LDSF = S2Z * STG_P;         // 12288 floats = 49152 B -> 3 blk/CU

constexpr int GX = WW / TX;               // 5
constexpr int GY = HH / TY;               // 24
constexpr int GZ = (DD / TZ) * BB;        // 80
constexpr int NBLK = GX * GY * GZ;        // 9600 (divisible by 8)
constexpr int CHUNK = NBLK / 8;           // 1200 blocks per XCD

__device__ __forceinline__ void gld_lds4(const float* g, float* l) {
    __builtin_amdgcn_global_load_lds(
        (const __attribute__((address_space(1))) void*)g,
        (__attribute__((address_space(3))) void*)l, 4, 0, 0);
}

// XCD-chunked swizzle (bijective: NBLK % 8 == 0)
__device__ __forceinline__ void tile_coords(int& x0, int& y0, int& z0, int& b) {
    const int lid = blockIdx.x + GX * (blockIdx.y + GY * blockIdx.z);
    const int nl  = (lid & 7) * CHUNK + (lid >> 3);
    const int bx  = nl % GX;
    int r = nl / GX;
    const int by  = r % GY;
    r /= GY;
    b  = r / (DD / TZ);
    x0 = bx * TX;
    y0 = by * TY;
    z0 = (r % (DD / TZ)) * TZ;
}

// in-plane part of the staged-source offset for tile element (syi,sxi), halo 2
__device__ __forceinline__ int row_term2(int syi, int sxi, int x0, int y0,
                                         bool border) {
    if (!border) return (y0 - 2 + syi) * WW + (x0 - 2 + sxi);
    const int gy = min(max(y0 - 2 + syi, 0), HH - 1);
    const int gx = min(max(x0 - 2 + sxi, 0), WW - 1);
    return gy * WW + gx;
}

// One trilinear pull at base coords (Z,Y,X) reading voxel (sz,sy,sx) of a
// tile with float slice-stride SP and row-stride RS (voxel slot = 3 floats).
// Returns via oz/oy/ox. vz/vy/vx are the (already scaled) displacements.
__device__ __forceinline__ void pull_core(const float* lds, int ownf,
                                          float vz, float vy, float vx,
                                          int Z, int Y, int X,
                                          int SP, int RS,
                                          float& oz, float& oy, float& ox) {
    const float cz = (float)Z + vz, cy = (float)Y + vy, cx = (float)X + vx;
    const bool jz = vz < 0.f, jy = vy < 0.f, jx = vx < 0.f;
    const float gzf = jz ? vz + 1.f : vz;
    const float gyf = jy ? vy + 1.f : vy;
    const float gxf = jx ? vx + 1.f : vx;
    const bool inb = (cz >= 0.f) & (cz <= (float)(DD - 1)) &
                     (cy >= 0.f) & (cy <= (float)(HH - 1)) &
                     (cx >= 0.f) & (cx <= (float)(WW - 1));
    const float m = inb ? 1.f : 0.f;
    const float wz1 = gzf * m, wz0 = m - wz1;
    const float wy1 = gyf, wy0 = 1.f - gyf;
    const float wx1 = gxf, wx0 = 1.f - gxf;
    const int sb = ((ownf - (jx ? 3 : 0)) - (jy ? RS : 0)) - (jz ? SP : 0);
    oz = 0.f; oy = 0.f; ox = 0.f;
    #pragma unroll
    for (int dz = 0; dz < 2; ++dz) {
        const float wzv = dz ? wz1 : wz0;
        #pragma unroll
        for (int dy = 0; dy < 2; ++dy) {
            const float wzy = wzv * (dy ? wy1 : wy0);
            const float w0 = wzy * wx0, w1 = wzy * wx1;
            const int o = sb + dz * SP + dy * RS;
            oz += lds[o]     * w0; oy += lds[o + 1] * w0; ox += lds[o + 2] * w0;
            oz += lds[o + 3] * w1; oy += lds[o + 4] * w1; ox += lds[o + 5] * w1;
        }
    }
}

// Fused 2-step kernel. IN_PLANAR: source is planar (B,3,D,H,W) raw flow,
// scale applied in the intermediate phase. OUT_PLANAR: final planar store.
template<int IN_PLANAR, int OUT_PLANAR>
__global__ __launch_bounds__(256, 3) void flow_fused(const float* __restrict__ vin,
                                                     float* __restrict__ vout,
                                                     float scale) {
    __shared__ float lds[LDSF];
    const int tid = threadIdx.x;
    int x0, y0, z0, b;
    tile_coords(x0, y0, z0, b);
    const bool border = (x0 == 0) | (x0 + TX >= WW) |
                        (y0 == 0) | (y0 + TY >= HH) |
                        (z0 < 2)  | (z0 + TZ + 2 > DD);
    const float* vb = vin + (IN_PLANAR ? b * 3 * PLANE : b * PLANE * 3);

    // ---- hoisted per-thread staging offsets (6 slots, slice-invariant) ----
    int g[STG_K];
    #pragma unroll
    for (int k = 0; k < STG_K; ++k) {
        const int Lc = min(tid + k * 256, STG_SLICE - 1);  // pad: dup read
        const int vox = Lc / 3;
        const int ch  = Lc - vox * 3;
        const int a   = vox / S2X;
        const int rt  = row_term2(a, vox - a * S2X, x0, y0, border);
        g[k] = IN_PLANAR ? (ch * PLANE + rt) : (rt * 3 + ch);
    }

    // ---- stage v_k (halo 2), full-wave DMA ----
    #pragma unroll
    for (int szi = 0; szi < S2Z; ++szi) {
        int zb = z0 - 2 + szi;
        if (border) zb = min(max(zb, 0), DD - 1);          // slice-uniform
        const float* sp = vb + (IN_PLANAR ? zb * HW : zb * (HW * 3));
        float* lb = lds + szi * STG_P;
        #pragma unroll
        for (int k = 0; k < STG_K; ++k)
            gld_lds4(sp + g[k], lb + tid + k * 256);
    }
    __syncthreads();

    // ---- phase 1: v_{k+1} on the halo-1 tile, into registers ----
    // Halo positions evaluated at CLAMPED absolute coords == what the
    // unfused next step would have staged (row_term clamp semantics).
    float ri[NIT][3];
    #pragma unroll
    for (int w = 0; w < NIT; ++w) {
        const int idx = min(tid + w * 256, NI - 1);        // tail: dup compute
        const int sz1 = idx / S1YX;
        const int r   = idx - sz1 * S1YX;
        const int sy1 = r / S1X;
        const int sx1 = r - sy1 * S1X;
        const int Zc = min(max(z0 - 1 + sz1, 0), DD - 1);
        const int Yc = min(max(y0 - 1 + sy1, 0), HH - 1);
        const int Xc = min(max(x0 - 1 + sx1, 0), WW - 1);
        const int sz2 = Zc - z0 + 2, sy2 = Yc - y0 + 2, sx2 = Xc - x0 + 2;
        const int ownf = sz2 * STG_P + 3 * (sy2 * S2X + sx2);
        float vz = lds[ownf], vy = lds[ownf + 1], vx = lds[ownf + 2];
        if (IN_PLANAR) { vz *= scale; vy *= scale; vx *= scale; }
        float oz, oy, ox;
        pull_core(lds, ownf, vz, vy, vx, Zc, Yc, Xc,
                  STG_P, 3 * S2X, oz, oy, ox);
        if (IN_PLANAR) { oz *= scale; oy *= scale; ox *= scale; }
        ri[w][0] = oz; ri[w][1] = oy; ri[w][2] = ox;
    }
    __syncthreads();   // all staged reads complete before overwrite

    // ---- write v_{k+1} into LDS (overwrites staged region) ----
    #pragma unroll
    for (int w = 0; w < NIT; ++w) {
        const int idx = min(tid + w * 256, NI - 1);        // dup lanes: same value
        const int sz1 = idx / S1YX;
        const int r   = idx - sz1 * S1YX;
        const int a   = sz1 * INT_P + 3 * r;
        lds[a] = ri[w][0]; lds[a + 1] = ri[w][1]; lds[a + 2] = ri[w][2];
    }
    __syncthreads();

    // ---- phase 2: v_{k+2} on the core tile, store to global ----
    const int tx = tid & (TX - 1), ty = tid >> 5;
    const int x = x0 + tx, y = y0 + ty;
    #pragma unroll
    for (int zz = 0; zz < TZ; ++zz) {
        const int z = z0 + zz;
        const int ownf = (zz + 1) * INT_P + 3 * ((ty + 1) * S1X + (tx + 1));
        const float vz = lds[ownf], vy = lds[ownf + 1], vx = lds[ownf + 2];
        float oz, oy, ox;
        pull_core(lds, ownf, vz, vy, vx, z, y, x,
                  INT_P, 3 * S1X, oz, oy, ox);
        if (OUT_PLANAR) {
            float* op = vout + b * 3 * PLANE + (z * HH + y) * WW + x;
            op[0] = oz; op[PLANE] = oy; op[2 * PLANE] = ox;
        } else {
            float t[3] = { oz, oy, ox };
            __builtin_memcpy(vout + (((b * DD + z) * HH + y) * WW + x) * 3,
                             t, 12);
        }
    }
}

extern "C" void kernel_launch(void* const* d_in, const int* in_sizes, int n_in,
                              void* d_out, int out_size, void* d_ws, size_t ws_size,
                              hipStream_t stream) {
    const float* flow = (const float*)d_in[0];
    float* out = (float*)d_out;   // packed scratch + final planar output
    float* wsA = (float*)d_ws;    // packed scratch (118 MB)

    dim3 blk(256);
    dim3 grd(GX, GY, GZ);         // 5 x 24 x 80
    const float s = 1.f / 256.f;  // 1 / 2^NSTEPS

    flow_fused<1, 0><<<grd, blk, 0, stream>>>(flow, wsA, s);   // steps 1-2
    flow_fused<0, 0><<<grd, blk, 0, stream>>>(wsA, out, 1.f);  // steps 3-4
    flow_fused<0, 0><<<grd, blk, 0, stream>>>(out, wsA, 1.f);  // steps 5-6
    flow_fused<0, 1><<<grd, blk, 0, stream>>>(wsA, out, 1.f);  // steps 7-8
}

// Round 19
// 392.454 us; speedup vs baseline: 1.3378x; 1.3378x over previous
//
#include <hip/hip_runtime.h>

// FlowExp: v = flow/2^8; repeat 8x: v <- trilinear_pull(v, identity + v)
// Invariant: ||v||inf <= max|flow|/256 ~ 0.023 < 1 for all steps, so
// floor(x+vx) in {x-1, x}: sign tests instead of floor/mod/clamp, halo 1
// always covers the corners, out-of-bounds folded into z-weights (m=0).
//
// R19: revert R18 fusion (conflicts scale with gather volume -> LDS pipe is
// the mids' binder; fusion trades cheap HBM for expensive LDS). Mid restored
// to R13 verbatim (43us, ~93% of LDS-pipe model). flow_first experiment:
// its 82us (2x mid, same LDS work) is invariant to layout/FETCH -> suspect
// VMEM stream interleaving (30 short streams: 3 planes x 10 slices, 136B
// segments). Channel-major LDS ([ch][3584]) makes staging 3 MONOTONE
// passes, one channel-plane each; per-lane z-clamp folded into hoisted
// offsets. Gather math unchanged (R13-proven).

#define BB 2
#define DD 160
#define HH 192
#define WW 160

constexpr int HW    = HH * WW;          // 30720
constexpr int PLANE = DD * HW;          // 4,915,200
constexpr int TX = 32, TY = 8, TZ = 8;
constexpr int SX = TX + 2, SY = TY + 2, SZ = TZ + 2;   // 34 x 10 x 10
constexpr int SYX  = SY * SX;           // 340 voxels per z-slice of the tile

// mid (interleaved) LDS geometry — R13 verbatim
constexpr int SLICE   = 3 * SYX;        // 1020 payload floats per slice
constexpr int SLICE_P = 1024;           // padded slice stride
constexpr int LDSF = SZ * SLICE_P;      // 10240 floats = 40960 B -> 4 blk/CU

// flow_first (channel-major SoA) LDS geometry
constexpr int CH_VOX = SZ * SYX;        // 3400 voxels per channel
constexpr int CH_P   = 3584;            // padded channel stride (14 x 256)
constexpr int KIT1   = CH_P / 256;      // 14 full-wave issues per channel
constexpr int LDSF1  = 3 * CH_P;        // 10752 floats = 43008 B -> 3 blk/CU

constexpr int GX = WW / TX;             // 5
constexpr int GY = HH / TY;             // 24
constexpr int GZ = (DD / TZ) * BB;      // 40
constexpr int NBLK  = GX * GY * GZ;     // 4800 (divisible by 8)
constexpr int CHUNK = NBLK / 8;         // 600 blocks per XCD

__device__ __forceinline__ void gld_lds4(const float* g, float* l) {
    __builtin_amdgcn_global_load_lds(
        (const __attribute__((address_space(1))) void*)g,
        (__attribute__((address_space(3))) void*)l, 4, 0, 0);
}

// XCD-chunked swizzle: contiguous CHUNK of tile-space per XCD (bijective).
__device__ __forceinline__ void tile_coords(int& x0, int& y0, int& z0, int& b) {
    const int lid = blockIdx.x + GX * (blockIdx.y + GY * blockIdx.z);
    const int nl  = (lid & 7) * CHUNK + (lid >> 3);
    const int bx  = nl % GX;
    int r = nl / GX;
    const int by  = r % GY;
    r /= GY;                 // 0..GZ-1
    b  = r / (DD / TZ);
    x0 = bx * TX;
    y0 = by * TY;
    z0 = (r % (DD / TZ)) * TZ;
}

// in-plane (y,x) part of the global voxel offset for tile element (syi,sxi)
__device__ __forceinline__ int row_term(int syi, int sxi, int x0, int y0,
                                        bool border) {
    if (!border) return (y0 - 1 + syi) * WW + (x0 - 1 + sxi);
    const int gy = min(max(y0 - 1 + syi, 0), HH - 1);
    const int gx = min(max(x0 - 1 + sxi, 0), WW - 1);
    return gy * WW + gx;
}

// ---------------- step 1: planar flow -> packed interleaved ----------------
// Channel-major SoA LDS: [ch][CH_P]. Staging = 3 monotone passes, one
// channel-plane each (14 full-wave DMA issues/channel). Per-lane z folded
// into hoisted offsets. RAW values; 1/256 folded at consumption.
__global__ __launch_bounds__(256, 3) void flow_first(const float* __restrict__ vin,
                                                     float* __restrict__ vout,
                                                     float scale) {
    __shared__ float lds[LDSF1];
    const int tid = threadIdx.x;
    int x0, y0, z0, b;
    tile_coords(x0, y0, z0, b);
    const bool border = (x0 == 0) | (x0 + TX >= WW) |
                        (y0 == 0) | (y0 + TY >= HH) |
                        (z0 == 0) | (z0 + TZ >= DD);
    const float* vb = vin + b * 3 * PLANE;

    // hoisted per-thread within-channel offsets (z included, 14 slots)
    int g[KIT1];
    #pragma unroll
    for (int k = 0; k < KIT1; ++k) {
        const int e = min(tid + k * 256, CH_VOX - 1);   // pad: safe dup read
        const int sl = e / SYX;
        const int r  = e - sl * SYX;
        const int a  = r / SX;
        int zb = z0 - 1 + sl;
        if (border) zb = min(max(zb, 0), DD - 1);
        g[k] = zb * HW + row_term(a, r - a * SX, x0, y0, border);
    }

    // 3 monotone staging passes (one channel plane each)
    #pragma unroll
    for (int c = 0; c < 3; ++c) {
        const float* cp = vb + c * PLANE;
        float* lb = lds + c * CH_P;
        #pragma unroll
        for (int k = 0; k < KIT1; ++k)
            gld_lds4(cp + g[k], lb + tid + k * 256);    // full-wave, no mask
    }
    __syncthreads();

    const int tx = tid & (TX - 1), ty = tid >> 5;
    const int x = x0 + tx, y = y0 + ty;
    #pragma unroll 2
    for (int zz = 0; zz < TZ; ++zz) {
        const int z = z0 + zz;
        const int so = (zz + 1) * SYX + (ty + 1) * SX + (tx + 1);
        const float vz = lds[so] * scale;               // scaled displacement
        const float vy = lds[CH_P + so] * scale;
        const float vx = lds[2 * CH_P + so] * scale;
        const float cz = (float)z + vz, cy = (float)y + vy, cx = (float)x + vx;
        const bool jz = vz < 0.f, jy = vy < 0.f, jx = vx < 0.f;
        const float gzf = jz ? vz + 1.f : vz;
        const float gyf = jy ? vy + 1.f : vy;
        const float gxf = jx ? vx + 1.f : vx;
        const bool inb = (cz >= 0.f) & (cz <= (float)(DD - 1)) &
                         (cy >= 0.f) & (cy <= (float)(HH - 1)) &
                         (cx >= 0.f) & (cx <= (float)(WW - 1));
        const float m = inb ? 1.f : 0.f;
        const float wz1 = gzf * m, wz0 = m - wz1;
        const float wy1 = gyf, wy0 = 1.f - gyf;
        const float wx1 = gxf, wx0 = 1.f - gxf;
        const int sb = ((so - (jx ? 1 : 0)) - (jy ? SX : 0))
                       - (jz ? SYX : 0);
        float oz = 0.f, oy = 0.f, ox = 0.f;
        #pragma unroll
        for (int dz = 0; dz < 2; ++dz) {
            const float wzv = dz ? wz1 : wz0;
            #pragma unroll
            for (int dy = 0; dy < 2; ++dy) {
                const float wzy = wzv * (dy ? wy1 : wy0);
                const float w0 = wzy * wx0, w1 = wzy * wx1;
                const int o = sb + dz * SYX + dy * SX;
                oz += lds[o] * w0;
                oy += lds[CH_P + o] * w0;
                ox += lds[2 * CH_P + o] * w0;
                oz += lds[o + 1] * w1;
                oy += lds[CH_P + o + 1] * w1;
                ox += lds[2 * CH_P + o + 1] * w1;
            }
        }
        // raw-value accumulation -> apply scale once (FP reorder << threshold)
        float t[3] = { oz * scale, oy * scale, ox * scale };
        __builtin_memcpy(vout + (((b * DD + z) * HH + y) * WW + x) * 3, t, 12);
    }
}

// ------------- steps 2..8: packed interleaved in, DMA staging --------------
// R13 verbatim. LDS slice: interleaved [voxel0 zyx][voxel1 zyx]...[pad 4].
// OUT_PLANAR: final step writes (B,3,D,H,W)
template<int OUT_PLANAR>
__global__ __launch_bounds__(256, 4) void flow_mid(const float* __restrict__ vin,
                                                   float* __restrict__ vout) {
    __shared__ float lds[LDSF];
    const int tid = threadIdx.x;
    int x0, y0, z0, b;
    tile_coords(x0, y0, z0, b);
    const bool border = (x0 == 0) | (x0 + TX >= WW) |
                        (y0 == 0) | (y0 + TY >= HH) |
                        (z0 == 0) | (z0 + TZ >= DD);
    const float* vb = vin + b * PLANE * 3;

    // per-thread slice-local offsets (4 slots): local = 3*vox + ch.
    int g0, g1, g2, g3;
    {
        const int l0 = tid;
        int v = l0 / 3, c = l0 - v * 3, a = v / SX;
        g0 = row_term(a, v - a * SX, x0, y0, border) * 3 + c;
        const int l1 = tid + 256;
        v = l1 / 3; c = l1 - v * 3; a = v / SX;
        g1 = row_term(a, v - a * SX, x0, y0, border) * 3 + c;
        const int l2 = tid + 512;
        v = l2 / 3; c = l2 - v * 3; a = v / SX;
        g2 = row_term(a, v - a * SX, x0, y0, border) * 3 + c;
        const int l3 = min(tid + 768, SLICE - 1);   // pad lanes: safe dup read
        v = l3 / 3; c = l3 - v * 3; a = v / SX;
        g3 = row_term(a, v - a * SX, x0, y0, border) * 3 + c;
    }

    #pragma unroll
    for (int szi = 0; szi < SZ; ++szi) {
        int zb = z0 - 1 + szi;
        if (border) zb = min(max(zb, 0), DD - 1);   // slice-uniform
        const float* sp = vb + zb * (HW * 3);
        float* lb = lds + szi * SLICE_P;
        gld_lds4(sp + g0, lb + tid);                // all full-wave, no mask
        gld_lds4(sp + g1, lb + tid + 256);
        gld_lds4(sp + g2, lb + tid + 512);
        gld_lds4(sp + g3, lb + tid + 768);          // lanes 252..255 -> pad
    }
    __syncthreads();

    const int tx = tid & (TX - 1), ty = tid >> 5;
    const int x = x0 + tx, y = y0 + ty;
    #pragma unroll 2
    for (int zz = 0; zz < TZ; ++zz) {
        const int z = z0 + zz;
        const int so = (zz + 1) * SLICE_P + 3 * ((ty + 1) * SX + (tx + 1));
        const float vz = lds[so], vy = lds[so + 1], vx = lds[so + 2];
        const float cz = (float)z + vz, cy = (float)y + vy, cx = (float)x + vx;
        const bool jz = vz < 0.f, jy = vy < 0.f, jx = vx < 0.f;
        const float gzf = jz ? vz + 1.f : vz;
        const float gyf = jy ? vy + 1.f : vy;
        const float gxf = jx ? vx + 1.f : vx;
        const bool inb = (cz >= 0.f) & (cz <= (float)(DD - 1)) &
                         (cy >= 0.f) & (cy <= (float)(HH - 1)) &
                         (cx >= 0.f) & (cx <= (float)(WW - 1));
        const float m = inb ? 1.f : 0.f;
        const float wz1 = gzf * m, wz0 = m - wz1;
        const float wy1 = gyf, wy0 = 1.f - gyf;
        const float wx1 = gxf, wx0 = 1.f - gxf;
        const int sb = ((so - (jx ? 3 : 0)) - (jy ? 3 * SX : 0))
                       - (jz ? SLICE_P : 0);
        float oz = 0.f, oy = 0.f, ox = 0.f;
        #pragma unroll
        for (int dz = 0; dz < 2; ++dz) {
            const float wzv = dz ? wz1 : wz0;
            #pragma unroll
            for (int dy = 0; dy < 2; ++dy) {
                const float wzy = wzv * (dy ? wy1 : wy0);
                const float w0 = wzy * wx0, w1 = wzy * wx1;
                const int o = sb + dz * SLICE_P + dy * (3 * SX);
                oz += lds[o]     * w0; oy += lds[o + 1] * w0; ox += lds[o + 2] * w0;
                oz += lds[o + 3] * w1; oy += lds[o + 4] * w1; ox += lds[o + 5] * w1;
            }
        }
        if (OUT_PLANAR) {
            float* op = vout + b * 3 * PLANE + (z * HH + y) * WW + x;
            op[0] = oz; op[PLANE] = oy; op[2 * PLANE] = ox;
        } else {
            float t[3] = { oz, oy, ox };
            __builtin_memcpy(vout + (((b * DD + z) * HH + y) * WW + x) * 3, t, 12);
        }
    }
}

extern "C" void kernel_launch(void* const* d_in, const int* in_sizes, int n_in,
                              void* d_out, int out_size, void* d_ws, size_t ws_size,
                              hipStream_t stream) {
    const float* flow = (const float*)d_in[0];
    float* out = (float*)d_out;   // packed scratch for even steps + final planar
    float* wsA = (float*)d_ws;    // packed scratch (118 MB)

    dim3 blk(256);
    dim3 grd(GX, GY, GZ);         // 5 x 24 x 40
    const float s = 1.f / 256.f;  // 1 / 2^NSTEPS

    flow_first<<<grd, blk, 0, stream>>>(flow, wsA, s);
    flow_mid<0><<<grd, blk, 0, stream>>>(wsA, out);
    flow_mid<0><<<grd, blk, 0, stream>>>(out, wsA);
    flow_mid<0><<<grd, blk, 0, stream>>>(wsA, out);
    flow_mid<0><<<grd, blk, 0, stream>>>(out, wsA);
    flow_mid<0><<<grd, blk, 0, stream>>>(wsA, out);
    flow_mid<0><<<grd, blk, 0, stream>>>(out, wsA);
    flow_mid<1><<<grd, blk, 0, stream>>>(wsA, out);
}

// Round 20
// 387.669 us; speedup vs baseline: 1.3543x; 1.0123x over previous
//
#include <hip/hip_runtime.h>

// FlowExp: v = flow/2^8; repeat 8x: v <- trilinear_pull(v, identity + v)
// Invariant: ||v||inf <= max|flow|/256 ~ 0.023 < 1 for all steps, so
// floor(x+vx) in {x-1, x}: sign tests instead of floor/mod/clamp, halo 1
// always covers the corners, out-of-bounds folded into z-weights (m=0).
//
// R20 (final): restore R13, the best-measured configuration (384us).
//  - flow_first (82us): SoA-slice LDS, full-wave padded DMA. At its
//    cold-first-touch traffic floor (proven invariant across 6 variants).
//  - flow_mid (43us x7): interleaved-slice LDS, ~93% of the LDS-pipe model
//    (reads + layout-invariant conflict cycles). Overlap/occupancy/b128/
//    fusion all null or negative.
// Techniques: full-wave padded-slice global_load_lds DMA (R13), hoisted
// per-thread addressing (R12), XCD-chunked block swizzle (R11, FETCH
// 187->63MB), sign-test gather (R4), convex-combination halo-1 bound.

#define BB 2
#define DD 160
#define HH 192
#define WW 160

constexpr int HW    = HH * WW;          // 30720
constexpr int PLANE = DD * HW;          // 4,915,200
constexpr int TX = 32, TY = 8, TZ = 8;
constexpr int SX = TX + 2, SY = TY + 2, SZ = TZ + 2;   // 34 x 10 x 10
constexpr int SYX  = SY * SX;           // 340 voxels per z-slice of the tile
constexpr int SLICE   = 3 * SYX;        // 1020 payload floats per slice
constexpr int SLICE_P = 1024;           // padded slice stride in LDS
constexpr int LDSF = SZ * SLICE_P;      // 10240 floats = 40960 B -> 4 blk/CU

constexpr int GX = WW / TX;             // 5
constexpr int GY = HH / TY;             // 24
constexpr int GZ = (DD / TZ) * BB;      // 40
constexpr int NBLK  = GX * GY * GZ;     // 4800 (divisible by 8)
constexpr int CHUNK = NBLK / 8;         // 600 blocks per XCD

__device__ __forceinline__ void gld_lds4(const float* g, float* l) {
    __builtin_amdgcn_global_load_lds(
        (const __attribute__((address_space(1))) void*)g,
        (__attribute__((address_space(3))) void*)l, 4, 0, 0);
}

// XCD-chunked swizzle: contiguous CHUNK of tile-space per XCD (bijective).
__device__ __forceinline__ void tile_coords(int& x0, int& y0, int& z0, int& b) {
    const int lid = blockIdx.x + GX * (blockIdx.y + GY * blockIdx.z);
    const int nl  = (lid & 7) * CHUNK + (lid >> 3);
    const int bx  = nl % GX;
    int r = nl / GX;
    const int by  = r % GY;
    r /= GY;                 // 0..GZ-1
    b  = r / (DD / TZ);
    x0 = bx * TX;
    y0 = by * TY;
    z0 = (r % (DD / TZ)) * TZ;
}

// in-plane (y,x) part of the global voxel offset for tile element (syi,sxi)
__device__ __forceinline__ int row_term(int syi, int sxi, int x0, int y0,
                                        bool border) {
    if (!border) return (y0 - 1 + syi) * WW + (x0 - 1 + sxi);
    const int gy = min(max(y0 - 1 + syi, 0), HH - 1);
    const int gx = min(max(x0 - 1 + sxi, 0), WW - 1);
    return gy * WW + gx;
}

// ---------------- step 1: planar flow -> packed interleaved ----------------
// SoA slice layout: [ch0 340][ch1 340][ch2 340][pad 4]. RAW values; the
// 1/256 scale folded at consumption (displacement and final output).
__global__ __launch_bounds__(256, 4) void flow_first(const float* __restrict__ vin,
                                                     float* __restrict__ vout,
                                                     float scale) {
    __shared__ float lds[LDSF];
    const int tid = threadIdx.x;
    int x0, y0, z0, b;
    tile_coords(x0, y0, z0, b);
    const bool border = (x0 == 0) | (x0 + TX >= WW) |
                        (y0 == 0) | (y0 + TY >= HH) |
                        (z0 == 0) | (z0 + TZ >= DD);
    const float* vb = vin + b * 3 * PLANE;

    // per-thread slice-local offsets (4 slots), invariant across z-slices.
    // local = ch*340 + syi*34 + sxi ; global ofs = ch*PLANE + row_term.
    int g0, g1, g2, g3;
    {
        const int l0 = tid;
        int c = l0 / SYX, r = l0 - c * SYX, a = r / SX;
        g0 = c * PLANE + row_term(a, r - a * SX, x0, y0, border);
        const int l1 = tid + 256;
        c = l1 / SYX; r = l1 - c * SYX; a = r / SX;
        g1 = c * PLANE + row_term(a, r - a * SX, x0, y0, border);
        const int l2 = tid + 512;
        c = l2 / SYX; r = l2 - c * SYX; a = r / SX;
        g2 = c * PLANE + row_term(a, r - a * SX, x0, y0, border);
        const int l3 = min(tid + 768, SLICE - 1);   // pad lanes: safe dup read
        c = l3 / SYX; r = l3 - c * SYX; a = r / SX;
        g3 = c * PLANE + row_term(a, r - a * SX, x0, y0, border);
    }

    #pragma unroll
    for (int szi = 0; szi < SZ; ++szi) {
        int zb = z0 - 1 + szi;
        if (border) zb = min(max(zb, 0), DD - 1);   // slice-uniform
        const float* sp = vb + zb * HW;
        float* lb = lds + szi * SLICE_P;
        gld_lds4(sp + g0, lb + tid);                // all full-wave, no mask
        gld_lds4(sp + g1, lb + tid + 256);
        gld_lds4(sp + g2, lb + tid + 512);
        gld_lds4(sp + g3, lb + tid + 768);          // lanes 252..255 -> pad
    }
    __syncthreads();

    const int tx = tid & (TX - 1), ty = tid >> 5;
    const int x = x0 + tx, y = y0 + ty;
    #pragma unroll 2
    for (int zz = 0; zz < TZ; ++zz) {
        const int z = z0 + zz;
        const int so = (zz + 1) * SLICE_P + (ty + 1) * SX + (tx + 1);
        const float vz = lds[so] * scale;           // scaled displacement
        const float vy = lds[so + SYX] * scale;
        const float vx = lds[so + 2 * SYX] * scale;
        const float cz = (float)z + vz, cy = (float)y + vy, cx = (float)x + vx;
        const bool jz = vz < 0.f, jy = vy < 0.f, jx = vx < 0.f;
        const float gzf = jz ? vz + 1.f : vz;
        const float gyf = jy ? vy + 1.f : vy;
        const float gxf = jx ? vx + 1.f : vx;
        const bool inb = (cz >= 0.f) & (cz <= (float)(DD - 1)) &
                         (cy >= 0.f) & (cy <= (float)(HH - 1)) &
                         (cx >= 0.f) & (cx <= (float)(WW - 1));
        const float m = inb ? 1.f : 0.f;
        const float wz1 = gzf * m, wz0 = m - wz1;
        const float wy1 = gyf, wy0 = 1.f - gyf;
        const float wx1 = gxf, wx0 = 1.f - gxf;
        const int sb = ((so - (jx ? 1 : 0)) - (jy ? SX : 0))
                       - (jz ? SLICE_P : 0);
        float oz = 0.f, oy = 0.f, ox = 0.f;
        #pragma unroll
        for (int dz = 0; dz < 2; ++dz) {
            const float wzv = dz ? wz1 : wz0;
            #pragma unroll
            for (int dy = 0; dy < 2; ++dy) {
                const float wzy = wzv * (dy ? wy1 : wy0);
                const float w0 = wzy * wx0, w1 = wzy * wx1;
                const int o = sb + dz * SLICE_P + dy * SX;
                oz += lds[o] * w0;
                oy += lds[o + SYX] * w0;
                ox += lds[o + 2 * SYX] * w0;
                oz += lds[o + 1] * w1;
                oy += lds[o + SYX + 1] * w1;
                ox += lds[o + 2 * SYX + 1] * w1;
            }
        }
        // raw-value accumulation -> apply scale once (FP reorder << threshold)
        float t[3] = { oz * scale, oy * scale, ox * scale };
        __builtin_memcpy(vout + (((b * DD + z) * HH + y) * WW + x) * 3, t, 12);
    }
}

// ------------- steps 2..8: packed interleaved in, DMA staging --------------
// LDS slice layout: interleaved [voxel0 zyx][voxel1 zyx]...[pad 4].
// OUT_PLANAR: final step writes (B,3,D,H,W)
template<int OUT_PLANAR>
__global__ __launch_bounds__(256, 4) void flow_mid(const float* __restrict__ vin,
                                                   float* __restrict__ vout) {
    __shared__ float lds[LDSF];
    const int tid = threadIdx.x;
    int x0, y0, z0, b;
    tile_coords(x0, y0, z0, b);
    const bool border = (x0 == 0) | (x0 + TX >= WW) |
                        (y0 == 0) | (y0 + TY >= HH) |
                        (z0 == 0) | (z0 + TZ >= DD);
    const float* vb = vin + b * PLANE * 3;

    // per-thread slice-local offsets (4 slots): local = 3*vox + ch.
    int g0, g1, g2, g3;
    {
        const int l0 = tid;
        int v = l0 / 3, c = l0 - v * 3, a = v / SX;
        g0 = row_term(a, v - a * SX, x0, y0, border) * 3 + c;
        const int l1 = tid + 256;
        v = l1 / 3; c = l1 - v * 3; a = v / SX;
        g1 = row_term(a, v - a * SX, x0, y0, border) * 3 + c;
        const int l2 = tid + 512;
        v = l2 / 3; c = l2 - v * 3; a = v / SX;
        g2 = row_term(a, v - a * SX, x0, y0, border) * 3 + c;
        const int l3 = min(tid + 768, SLICE - 1);   // pad lanes: safe dup read
        v = l3 / 3; c = l3 - v * 3; a = v / SX;
        g3 = row_term(a, v - a * SX, x0, y0, border) * 3 + c;
    }

    #pragma unroll
    for (int szi = 0; szi < SZ; ++szi) {
        int zb = z0 - 1 + szi;
        if (border) zb = min(max(zb, 0), DD - 1);   // slice-uniform
        const float* sp = vb + zb * (HW * 3);
        float* lb = lds + szi * SLICE_P;
        gld_lds4(sp + g0, lb + tid);                // all full-wave, no mask
        gld_lds4(sp + g1, lb + tid + 256);
        gld_lds4(sp + g2, lb + tid + 512);
        gld_lds4(sp + g3, lb + tid + 768);          // lanes 252..255 -> pad
    }
    __syncthreads();

    const int tx = tid & (TX - 1), ty = tid >> 5;
    const int x = x0 + tx, y = y0 + ty;
    #pragma unroll 2
    for (int zz = 0; zz < TZ; ++zz) {
        const int z = z0 + zz;
        const int so = (zz + 1) * SLICE_P + 3 * ((ty + 1) * SX + (tx + 1));
        const float vz = lds[so], vy = lds[so + 1], vx = lds[so + 2];
        const float cz = (float)z + vz, cy = (float)y + vy, cx = (float)x + vx;
        const bool jz = vz < 0.f, jy = vy < 0.f, jx = vx < 0.f;
        const float gzf = jz ? vz + 1.f : vz;
        const float gyf = jy ? vy + 1.f : vy;
        const float gxf = jx ? vx + 1.f : vx;
        const bool inb = (cz >= 0.f) & (cz <= (float)(DD - 1)) &
                         (cy >= 0.f) & (cy <= (float)(HH - 1)) &
                         (cx >= 0.f) & (cx <= (float)(WW - 1));
        const float m = inb ? 1.f : 0.f;
        const float wz1 = gzf * m, wz0 = m - wz1;
        const float wy1 = gyf, wy0 = 1.f - gyf;
        const float wx1 = gxf, wx0 = 1.f - gxf;
        const int sb = ((so - (jx ? 3 : 0)) - (jy ? 3 * SX : 0))
                       - (jz ? SLICE_P : 0);
        float oz = 0.f, oy = 0.f, ox = 0.f;
        #pragma unroll
        for (int dz = 0; dz < 2; ++dz) {
            const float wzv = dz ? wz1 : wz0;
            #pragma unroll
            for (int dy = 0; dy < 2; ++dy) {
                const float wzy = wzv * (dy ? wy1 : wy0);
                const float w0 = wzy * wx0, w1 = wzy * wx1;
                const int o = sb + dz * SLICE_P + dy * (3 * SX);
                oz += lds[o]     * w0; oy += lds[o + 1] * w0; ox += lds[o + 2] * w0;
                oz += lds[o + 3] * w1; oy += lds[o + 4] * w1; ox += lds[o + 5] * w1;
            }
        }
        if (OUT_PLANAR) {
            float* op = vout + b * 3 * PLANE + (z * HH + y) * WW + x;
            op[0] = oz; op[PLANE] = oy; op[2 * PLANE] = ox;
        } else {
            float t[3] = { oz, oy, ox };
            __builtin_memcpy(vout + (((b * DD + z) * HH + y) * WW + x) * 3, t, 12);
        }
    }
}

extern "C" void kernel_launch(void* const* d_in, const int* in_sizes, int n_in,
                              void* d_out, int out_size, void* d_ws, size_t ws_size,
                              hipStream_t stream) {
    const float* flow = (const float*)d_in[0];
    float* out = (float*)d_out;   // packed scratch for even steps + final planar
    float* wsA = (float*)d_ws;    // packed scratch (118 MB)

    dim3 blk(256);
    dim3 grd(GX, GY, GZ);         // 5 x 24 x 40
    const float s = 1.f / 256.f;  // 1 / 2^NSTEPS

    flow_first<<<grd, blk, 0, stream>>>(flow, wsA, s);
    flow_mid<0><<<grd, blk, 0, stream>>>(wsA, out);
    flow_mid<0><<<grd, blk, 0, stream>>>(out, wsA);
    flow_mid<0><<<grd, blk, 0, stream>>>(wsA, out);
    flow_mid<0><<<grd, blk, 0, stream>>>(out, wsA);
    flow_mid<0><<<grd, blk, 0, stream>>>(wsA, out);
    flow_mid<0><<<grd, blk, 0, stream>>>(out, wsA);
    flow_mid<1><<<grd, blk, 0, stream>>>(wsA, out);
}